// Round 1
// baseline (158.880 us; speedup 1.0000x reference)
//
#include <hip/hip_runtime.h>

// AnnularDilatedKNN: B=4, N=4096, C=64, SAMPLE=16, DILATED_RATE=2 -> NSAMPLE=32,
// radius^2 = 256. Output = concat(dilated_xyz [4,3,4096,16], dilated_feature [4,64,4096,16]).
//
// Strategy:
//  - one block (256 thr) per 16 consecutive points of one batch (1024 blocks)
//  - stage batch xyz (48KB) in LDS; wave-per-point ball query via __ballot +
//    scalar bit extraction (need hit ranks 0 and 16..30 only, early exit at 31)
//  - d2 arithmetic matches reference rounding: fp contract OFF, left-assoc sums
//  - gather phase: thread t owns output row (i,k)=t of the block's contiguous
//    256-element segment per (b,c) plane -> fully coalesced stores; feature rows
//    read as float4 (L2-resident).

#define BB 4
#define NN 4096
#define KK 16
#define NPB 16
#define THREADS 256
#define PLANE (NN * KK)   // 65536

__global__ __launch_bounds__(THREADS)
void annular_knn_kernel(const float* __restrict__ xyz,
                        const float* __restrict__ feat,
                        float* __restrict__ out)
{
#pragma clang fp contract(off)
    __shared__ float sxyz[NN * 3];
    __shared__ int   sids[NPB * KK];

    const int b    = blockIdx.x >> 8;            // 256 blocks per batch
    const int i0   = (blockIdx.x & 255) * NPB;   // first point of this block
    const int t    = threadIdx.x;
    const int lane = t & 63;
    const int wave = t >> 6;

    // ---- stage xyz[b] into LDS (coalesced scalar copy, 48 iters/thread) ----
    const float* xb = xyz + (size_t)b * (NN * 3);
    for (int e = t; e < NN * 3; e += THREADS) sxyz[e] = xb[e];
    __syncthreads();

    // ---- ball query: each wave handles 4 points sequentially ----
    for (int s = 0; s < NPB / 4; ++s) {
        const int p = wave * 4 + s;
        const int i = i0 + p;
        const float xi = sxyz[3 * i], yi = sxyz[3 * i + 1], zi = sxyz[3 * i + 2];
        const float sqi = (xi * xi + yi * yi) + zi * zi;
        const int pbase = p * KK;
        int cnt = 0, hit0 = 0;

        for (int jc = 0; jc < NN / 64; ++jc) {
            const int j = (jc << 6) + lane;
            const float xj = sxyz[3 * j], yj = sxyz[3 * j + 1], zj = sxyz[3 * j + 2];
            const float dot = (xi * xj + yi * yj) + zi * zj;   // matches np order
            const float sqj = (xj * xj + yj * yj) + zj * zj;
            const float d2  = (sqi + sqj) - 2.0f * dot;
            unsigned long long m = __ballot(d2 < 256.0f);
            if (m == 0ULL) continue;
            const int pc = __popcll(m);
            // all hits fall in ranks 1..15 -> nothing to record
            if (cnt > 0 && cnt + pc <= 16) { cnt += pc; continue; }
            while (m) {
                const int bit = __builtin_ctzll(m);
                m &= (m - 1);
                const int jj = (jc << 6) + bit;
                if (cnt == 0) hit0 = jj;
                else if (cnt >= 16) { if (lane == 0) sids[pbase + cnt - 15] = jj; }
                if (++cnt >= 31) break;
            }
            if (cnt >= 31) break;
        }
        if (lane == 0) {
            sids[pbase] = hit0;                       // center slot
            int s0 = cnt - 15; if (s0 < 1) s0 = 1;    // pad unfilled slots
            for (int q = s0; q < KK; ++q) sids[pbase + q] = hit0;
        }
    }
    __syncthreads();

    // ---- gather + coalesced write-out; thread t owns row (i,k) = t ----
    const int id = sids[t];
    const int ob = i0 * KK + t;   // offset inside each [N*K] plane

    // dilated_xyz [B,3,N,K]
    float* o0 = out + (size_t)b * 3 * PLANE + ob;
    o0[0]         = sxyz[3 * id];
    o0[PLANE]     = sxyz[3 * id + 1];
    o0[2 * PLANE] = sxyz[3 * id + 2];

    // dilated_feature [B,64,N,K]
    const float4* frow = reinterpret_cast<const float4*>(feat + ((size_t)b * NN + id) * 64);
    float* o1 = out + (size_t)BB * 3 * PLANE + (size_t)b * 64 * PLANE + ob;
#pragma unroll
    for (int q = 0; q < 16; ++q) {
        const float4 v = frow[q];
        float* oc = o1 + (size_t)(4 * q) * PLANE;
        oc[0]         = v.x;
        oc[PLANE]     = v.y;
        oc[2 * PLANE] = v.z;
        oc[3 * PLANE] = v.w;
    }
}

extern "C" void kernel_launch(void* const* d_in, const int* in_sizes, int n_in,
                              void* d_out, int out_size, void* d_ws, size_t ws_size,
                              hipStream_t stream) {
    const float* xyz  = (const float*)d_in[0];
    const float* feat = (const float*)d_in[1];
    float* out = (float*)d_out;
    dim3 grid(BB * (NN / NPB));   // 1024 blocks
    annular_knn_kernel<<<grid, THREADS, 0, stream>>>(xyz, feat, out);
}

// Round 2
// 130.632 us; speedup vs baseline: 1.2162x; 1.2162x over previous
//
#include <hip/hip_runtime.h>

// AnnularDilatedKNN: B=4, N=4096, C=64, SAMPLE=16, DILATED_RATE=2, r^2=256.
// Round 2: 3-kernel structure, no LDS, wave-per-point query with parallel
// rank extraction. Numerics bit-match the numpy reference: contract off,
// sq=(x*x+y*y)+z*z, dot=(xi*xj+yi*yj)+zi*zj, d2=(sqi+sqj)-2*dot.

#define BB 4
#define NN 4096
#define KK 16
#define PLANE (NN * KK)   // 65536

// ---------- K1: P[b*N+j] = (x, y, z, sq) ----------
__global__ __launch_bounds__(256)
void build_soa(const float* __restrict__ xyz, float4* __restrict__ P)
{
#pragma clang fp contract(off)
    const int g = blockIdx.x * 256 + threadIdx.x;      // 0..16383
    const float x = xyz[3 * g], y = xyz[3 * g + 1], z = xyz[3 * g + 2];
    const float sq = (x * x + y * y) + z * z;
    P[g] = make_float4(x, y, z, sq);
}

// ---------- K2: ball query, one wave per point ----------
__global__ __launch_bounds__(256)
void ball_query(const float4* __restrict__ P, int* __restrict__ ids)
{
#pragma clang fp contract(off)
    const int wid  = (blockIdx.x * 256 + threadIdx.x) >> 6;  // global wave = point
    const int lane = threadIdx.x & 63;
    const int b    = wid >> 12;                              // 4096 pts / batch
    const float4 pi = P[wid];
    const float sqi = pi.w;
    const unsigned long long lt = (1ULL << lane) - 1ULL;     // bits below lane
    int fj  = 0x7fffffff;   // this lane's first hit j
    int cnt = 0;            // uniform: total hits so far (capped use at 31)
    int* row = ids + wid * KK;
    const float4* Pb = P + (b << 12);

    for (int jc = 0; jc < NN / 64; ++jc) {
        const int j = (jc << 6) + lane;
        const float4 pj = Pb[j];
        const float dot = (pi.x * pj.x + pi.y * pj.y) + pi.z * pj.z;
        const float d2  = (sqi + pj.w) - 2.0f * dot;
        const bool hit  = d2 < 256.0f;
        unsigned long long m = __ballot(hit);
        if (m) {
            if (hit && fj == 0x7fffffff) fj = j;
            const int rank = cnt + __popcll(m & lt);         // this lane's hit rank
            if (hit && rank >= 16 && rank <= 30) row[rank - 15] = j;
            cnt += __popcll(m);
            if (cnt >= 31) break;                            // ranks 0..30 secured
        }
    }

    // hit0 = smallest hit j = wave-min of per-lane first hits
    for (int off = 32; off; off >>= 1) {
        const int o = __shfl_xor(fj, off, 64);
        fj = min(fj, o);
    }
    // slots 1..hi were filled by rank writes; pad the rest (and slot 0) with hit0
    const int hi = (cnt < 31 ? cnt : 31) - 16;
    if (lane < KK && (lane == 0 || lane > hi)) row[lane] = fj;
}

// ---------- K3: gather + coalesced write-out ----------
__global__ __launch_bounds__(256)
void gather_out(const float4* __restrict__ P, const float* __restrict__ feat,
                const int* __restrict__ ids, float* __restrict__ out)
{
    const int b  = blockIdx.x >> 8;             // 256 blocks per batch
    const int i0 = (blockIdx.x & 255) * 16;     // 16 points per block
    const int t  = threadIdx.x;                 // row (i,k) = (t>>4, t&15)
    const int id = ids[((b << 12) + i0) * KK + t];   // coalesced
    const int ob = i0 * KK + t;                 // offset inside each [N*K] plane

    const float4 p = P[(b << 12) + id];
    float* o0 = out + (size_t)b * 3 * PLANE + ob;
    o0[0]         = p.x;
    o0[PLANE]     = p.y;
    o0[2 * PLANE] = p.z;

    const float4* frow = reinterpret_cast<const float4*>(feat + ((size_t)(b << 12) + id) * 64);
    float* o1 = out + (size_t)BB * 3 * PLANE + (size_t)b * 64 * PLANE + ob;
#pragma unroll
    for (int q = 0; q < 16; ++q) {
        const float4 v = frow[q];
        float* oc = o1 + (size_t)(4 * q) * PLANE;
        oc[0]         = v.x;
        oc[PLANE]     = v.y;
        oc[2 * PLANE] = v.z;
        oc[3 * PLANE] = v.w;
    }
}

extern "C" void kernel_launch(void* const* d_in, const int* in_sizes, int n_in,
                              void* d_out, int out_size, void* d_ws, size_t ws_size,
                              hipStream_t stream) {
    const float* xyz  = (const float*)d_in[0];
    const float* feat = (const float*)d_in[1];
    float* out = (float*)d_out;

    float4* P  = (float4*)d_ws;                              // 16384 * 16 B = 256 KB
    int*    ids = (int*)((char*)d_ws + (size_t)BB * NN * 16); // 1 MB

    build_soa <<<BB * NN / 256, 256, 0, stream>>>(xyz, P);
    ball_query<<<BB * NN / 4,   256, 0, stream>>>(P, ids);   // 1 wave per point
    gather_out<<<BB * (NN / 16), 256, 0, stream>>>(P, feat, ids, out);
}

// Round 3
// 115.837 us; speedup vs baseline: 1.3716x; 1.1277x over previous
//
#include <hip/hip_runtime.h>

// AnnularDilatedKNN: B=4, N=4096, C=64, SAMPLE=16, DILATED_RATE=2, r^2=256.
// Round 3: build_soa + ONE fused query/gather kernel.
//  - 4 points per block (4 waves; wave-per-point ball query, 2-chunk unrolled,
//    next-pair prefetch), ids staged in LDS, then the whole block gathers its
//    4x16 output rows with coalesced stores. Gather overlaps query across blocks.
// Numerics bit-match numpy: contract off, sq=(x*x+y*y)+z*z,
// dot=(xi*xj+yi*yj)+zi*zj, d2=(sqi+sqj)-2*dot.

#define BB 4
#define NN 4096
#define KK 16
#define PLANE (NN * KK)   // 65536

// ---------- K1: P[b*N+j] = (x, y, z, sq) ----------
__global__ __launch_bounds__(256)
void build_soa(const float* __restrict__ xyz, float4* __restrict__ P)
{
#pragma clang fp contract(off)
    const int g = blockIdx.x * 256 + threadIdx.x;      // 0..16383
    const float x = xyz[3 * g], y = xyz[3 * g + 1], z = xyz[3 * g + 2];
    const float sq = (x * x + y * y) + z * z;
    P[g] = make_float4(x, y, z, sq);
}

// ---------- K2: fused ball query + gather ----------
// grid: 4096 blocks x 256 threads; block handles 4 consecutive points.
__global__ __launch_bounds__(256, 4)
void query_gather(const float4* __restrict__ P, const float* __restrict__ feat,
                  float* __restrict__ out)
{
#pragma clang fp contract(off)
    __shared__ int sids[4 * KK];

    const int beta = blockIdx.x;
    const int b    = beta >> 10;                 // 1024 blocks per batch
    const int p0   = (beta & 1023) * 4;          // first point (in batch) of block
    const int t    = threadIdx.x;
    const int lane = t & 63;
    const int wave = t >> 6;

    const float4* Pb = P + (b << 12);

    // ---- query phase: wave w handles point p0+w ----
    {
        const int   pl  = wave;                  // local point 0..3
        const float4 pi = Pb[p0 + pl];
        const float sqi = pi.w;
        const unsigned long long lt = (1ULL << lane) - 1ULL;
        int fj  = 0x7fffffff;
        int cnt = 0;
        int* row = sids + pl * KK;

        // prefetch first chunk pair
        float4 a = Pb[lane];
        float4 c = Pb[64 + lane];
        for (int jc = 0; jc < NN / 64; jc += 2) {
            float4 na, nc;
            if (jc + 2 < NN / 64) {
                na = Pb[((jc + 2) << 6) + lane];
                nc = Pb[((jc + 3) << 6) + lane];
            }
            const int j0 = (jc << 6) + lane;
            const int j1 = j0 + 64;
            const float dot0 = (pi.x * a.x + pi.y * a.y) + pi.z * a.z;
            const float d20  = (sqi + a.w) - 2.0f * dot0;
            const float dot1 = (pi.x * c.x + pi.y * c.y) + pi.z * c.z;
            const float d21  = (sqi + c.w) - 2.0f * dot1;
            const bool h0 = d20 < 256.0f;
            const bool h1 = d21 < 256.0f;
            const unsigned long long m0 = __ballot(h0);
            const unsigned long long m1 = __ballot(h1);
            if (m0 | m1) {
                if (fj == 0x7fffffff) { if (h0) fj = j0; else if (h1) fj = j1; }
                const int r0 = cnt + __popcll(m0 & lt);
                if (h0 && r0 >= 16 && r0 <= 30) row[r0 - 15] = j0;
                cnt += __popcll(m0);
                const int r1 = cnt + __popcll(m1 & lt);
                if (h1 && r1 >= 16 && r1 <= 30) row[r1 - 15] = j1;
                cnt += __popcll(m1);
                if (cnt >= 31) break;
            }
            a = na; c = nc;
        }

        // hit0 = smallest hit j across the wave
        for (int off = 32; off; off >>= 1) {
            const int o = __shfl_xor(fj, off, 64);
            fj = fj < o ? fj : o;
        }
        const int hi = (cnt < 31 ? cnt : 31) - 16;
        if (lane < KK && (lane == 0 || lane > hi)) row[lane] = fj;
    }
    __syncthreads();

    // ---- gather phase: thread t -> output row (t&63), channel quarter (t>>6) ----
    const int rowi = t & 63;                 // local (point, k) row
    const int part = t >> 6;                 // 16 channels each
    const int id   = sids[rowi];
    const int ob   = (beta & 1023) * 64 + rowi;   // offset inside each [N*K] plane

    if (part == 0) {                         // dilated_xyz [B,3,N,K]
        const float4 p = Pb[id];
        float* o0 = out + (size_t)b * 3 * PLANE + ob;
        o0[0]         = p.x;
        o0[PLANE]     = p.y;
        o0[2 * PLANE] = p.z;
    }

    // dilated_feature [B,64,N,K], channels [16*part, 16*part+16)
    const float4* frow = reinterpret_cast<const float4*>(feat + ((size_t)(b << 12) + id) * 64) + part * 4;
    float* o1 = out + (size_t)BB * 3 * PLANE + (size_t)b * 64 * PLANE
                    + (size_t)(part * 16) * PLANE + ob;
#pragma unroll
    for (int q = 0; q < 4; ++q) {
        const float4 v = frow[q];
        float* oc = o1 + (size_t)(4 * q) * PLANE;
        oc[0]         = v.x;
        oc[PLANE]     = v.y;
        oc[2 * PLANE] = v.z;
        oc[3 * PLANE] = v.w;
    }
}

extern "C" void kernel_launch(void* const* d_in, const int* in_sizes, int n_in,
                              void* d_out, int out_size, void* d_ws, size_t ws_size,
                              hipStream_t stream) {
    const float* xyz  = (const float*)d_in[0];
    const float* feat = (const float*)d_in[1];
    float* out = (float*)d_out;

    float4* P = (float4*)d_ws;                      // 16384 * 16 B = 256 KB

    build_soa   <<<BB * NN / 256, 256, 0, stream>>>(xyz, P);
    query_gather<<<BB * NN / 4,   256, 0, stream>>>(P, feat, out);
}